// Round 1
// baseline (119.012 us; speedup 1.0000x reference)
//
#include <hip/hip_runtime.h>

typedef _Float16 f16;
typedef f16 f16x8 __attribute__((ext_vector_type(8)));
typedef float f32x4 __attribute__((ext_vector_type(4)));

#define IMG_H 1024
#define IMG_W 1024
#define CIN 64
#define COUT_ 64
#define NBLK 32
#define NACT 512
#define EPS_ 1e-3f

// workspace layout
#define WT_ELEMS (18 * 4 * 64 * 8)   // 36864 f16 fragments
#define WT_BYTES (WT_ELEMS * 2)      // 73728 B
#define FLAGS_OFF WT_BYTES           // int flags[1024]

// Build per-lane MFMA B-fragments: wt[((kk*4 + wv)*64 + l)*8 + j]
//   kk = (ky*3+kx)*2 + half ; B[k][col] with k=(l>>4)*8+j (+half*32 cin), col=wv*16+(l&15)
__global__ void prep_weights_k(const float* __restrict__ w, f16* __restrict__ wt) {
    int t = blockIdx.x * 256 + threadIdx.x;
    if (t >= WT_ELEMS) return;
    int j  = t & 7;
    int l  = (t >> 3) & 63;
    int wv = (t >> 9) & 3;
    int kk = t >> 11;                 // 0..17
    int ky = kk / 6;
    int kx = (kk % 6) >> 1;
    int hf = kk & 1;
    int cin  = hf * 32 + ((l >> 4) << 3) + j;
    int cout = wv * 16 + (l & 15);
    wt[t] = (f16)w[((ky * 3 + kx) * CIN + cin) * COUT_ + cout];
}

__global__ void prep_flags_k(const int* __restrict__ abi, int* __restrict__ flags) {
    int t = blockIdx.x * 256 + threadIdx.x;
    if (t < NACT) {
        int bi = abi[3 * t + 1];
        int bj = abi[3 * t + 2];
        flags[bi * NBLK + bj] = 1;
    }
}

__global__ void zero_inactive_k(const int* __restrict__ flags, float* __restrict__ out) {
    int b = blockIdx.x;
    if (flags[b]) return;
    int bi = b >> 5, bj = b & 31;
    float4 z = make_float4(0.f, 0.f, 0.f, 0.f);
    float4* base = (float4*)(out + ((size_t)(bi * 32) * IMG_W + bj * 32) * COUT_);
    for (int it = threadIdx.x; it < 32 * 512; it += 256) {
        int r  = it >> 9;               // row within block
        int c4 = it & 511;              // float4 within 32*64-float row span
        base[(size_t)r * (IMG_W * COUT_ / 4) + c4] = z;
    }
}

__launch_bounds__(256, 2)
__global__ void sparse_conv_k(const float* __restrict__ inp,
                              const f16*  __restrict__ wt,
                              const float* __restrict__ cb,
                              const float* __restrict__ gamma,
                              const float* __restrict__ beta,
                              const float* __restrict__ rmean,
                              const float* __restrict__ rvar,
                              const int*  __restrict__ abi,
                              float* __restrict__ out) {
    // patch: 18 rows x 34 cols x 8 channel-groups of 16B (f16x8), XOR-swizzled
    __shared__ uint4 lds[18 * 34 * 8];   // 78336 B -> 2 wg/CU

    const int wg = blockIdx.x;
    const int ab = wg >> 1, yh = wg & 1;
    const int bi = abi[3 * ab + 1];
    const int bj = abi[3 * ab + 2];
    const int tid  = threadIdx.x;
    const int lane = tid & 63;
    const int wv   = tid >> 6;

    // ---- stage 18x34x64 patch (fp32 -> f16, swizzled channel groups) ----
    const int r0 = bi * 32 + yh * 16 - 1;   // unpadded top row
    const int c0 = bj * 32 - 1;             // unpadded left col
    for (int task = tid; task < 18 * 34 * 8; task += 256) {
        int g  = task & 7;
        int p  = task >> 3;
        int dr = p / 34;
        int dc = p - dr * 34;
        int row = r0 + dr, col = c0 + dc;
        float4 a = make_float4(0.f, 0.f, 0.f, 0.f), b = a;
        if ((unsigned)row < IMG_H && (unsigned)col < IMG_W) {
            const float4* src = (const float4*)(inp + (((size_t)row * IMG_W + col) * CIN + g * 8));
            a = src[0]; b = src[1];
        }
        f16x8 v;
        v[0] = (f16)a.x; v[1] = (f16)a.y; v[2] = (f16)a.z; v[3] = (f16)a.w;
        v[4] = (f16)b.x; v[5] = (f16)b.y; v[6] = (f16)b.z; v[7] = (f16)b.w;
        lds[(p << 3) + (g ^ (dc & 7))] = __builtin_bit_cast(uint4, v);
    }

    // ---- per-wave weight fragments (one 16-cout n-tile per wave) ----
    f16x8 wf[18];
    const uint4* wt4 = (const uint4*)wt;
    #pragma unroll
    for (int kk = 0; kk < 18; ++kk)
        wf[kk] = __builtin_bit_cast(f16x8, wt4[(kk * 4 + wv) * 64 + lane]);

    const int co = wv * 16 + (lane & 15);
    const float sc = gamma[co] * rsqrtf(rvar[co] + EPS_);
    const float sh = cb[co] * sc + beta[co] - rmean[co] * sc;

    __syncthreads();

    const int pi   = lane & 15;   // pixel within m-tile (A row)
    const int kgrp = lane >> 4;   // k-subgroup
    float* outb = out + (((size_t)(bi * 32 + yh * 16) * IMG_W) + bj * 32) * COUT_;

    for (int yrow = 0; yrow < 16; ++yrow) {
        f32x4 acc0 = {0.f, 0.f, 0.f, 0.f};
        f32x4 acc1 = {0.f, 0.f, 0.f, 0.f};
        #pragma unroll
        for (int kk = 0; kk < 18; ++kk) {
            const int ky = kk / 6;
            const int kx = (kk % 6) >> 1;
            const int hf = kk & 1;
            const int dr = yrow + ky;
            const int g  = hf * 4 + kgrp;
            const int dc0 = pi + kx;
            const int dc1 = pi + kx + 16;
            uint4 a0 = lds[((dr * 34 + dc0) << 3) + (g ^ (dc0 & 7))];
            uint4 a1 = lds[((dr * 34 + dc1) << 3) + (g ^ (dc1 & 7))];
            acc0 = __builtin_amdgcn_mfma_f32_16x16x32_f16(__builtin_bit_cast(f16x8, a0), wf[kk], acc0, 0, 0, 0);
            acc1 = __builtin_amdgcn_mfma_f32_16x16x32_f16(__builtin_bit_cast(f16x8, a1), wf[kk], acc1, 0, 0, 0);
        }
        #pragma unroll
        for (int r = 0; r < 4; ++r) {
            const int px0 = kgrp * 4 + r;
            float v0 = fmaxf(acc0[r] * sc + sh, 0.f);
            float v1 = fmaxf(acc1[r] * sc + sh, 0.f);
            outb[((size_t)yrow * IMG_W + px0) * COUT_ + co] = v0;
            outb[((size_t)yrow * IMG_W + px0 + 16) * COUT_ + co] = v1;
        }
    }
}

extern "C" void kernel_launch(void* const* d_in, const int* in_sizes, int n_in,
                              void* d_out, int out_size, void* d_ws, size_t ws_size,
                              hipStream_t stream) {
    const float* inp   = (const float*)d_in[0];
    const float* convw = (const float*)d_in[1];
    const float* convb = (const float*)d_in[2];
    const float* gamma = (const float*)d_in[3];
    const float* beta  = (const float*)d_in[4];
    const float* rmean = (const float*)d_in[5];
    const float* rvar  = (const float*)d_in[6];
    const int*   abi   = (const int*)d_in[7];
    float* out = (float*)d_out;

    f16* wt    = (f16*)d_ws;
    int* flags = (int*)((char*)d_ws + FLAGS_OFF);

    hipMemsetAsync(flags, 0, NBLK * NBLK * sizeof(int), stream);
    hipLaunchKernelGGL(prep_flags_k, dim3(2), dim3(256), 0, stream, abi, flags);
    hipLaunchKernelGGL(prep_weights_k, dim3((WT_ELEMS + 255) / 256), dim3(256), 0, stream, convw, wt);
    hipLaunchKernelGGL(zero_inactive_k, dim3(NBLK * NBLK), dim3(256), 0, stream, flags, out);
    hipLaunchKernelGGL(sparse_conv_k, dim3(NACT * 2), dim3(256), 0, stream,
                       inp, wt, convb, gamma, beta, rmean, rvar, abi, out);
}

// Round 2
// 108.847 us; speedup vs baseline: 1.0934x; 1.0934x over previous
//
#include <hip/hip_runtime.h>

typedef _Float16 f16;
typedef f16 f16x8 __attribute__((ext_vector_type(8)));
typedef float f32x16 __attribute__((ext_vector_type(16)));

#define IMG_H 1024
#define IMG_W 1024
#define CIN 64
#define COUT_ 64
#define NBLK 32
#define NACT 512
#define EPS_ 1e-3f

#define WT_ELEMS (36 * 2 * 64 * 8)   // 36864 f16 B-fragments

// B-fragments for mfma_f32_32x32x16_f16:
//   kstep ks = tap*4 + q  (tap = ky*3+kx, q selects 16 of 64 cin)
//   lane l, elem j:  k = (l>>5)*8 + j  ->  cin = q*16 + (l>>5)*8 + j
//   col = l&31       ->  cout = ch*32 + (l&31)   (ch = cout half)
__global__ void prep_weights_k(const float* __restrict__ w, f16* __restrict__ wt) {
    int t = blockIdx.x * 256 + threadIdx.x;
    if (t >= WT_ELEMS) return;
    int j  = t & 7;
    int l  = (t >> 3) & 63;
    int ch = (t >> 9) & 1;
    int ks = t >> 10;                 // 0..35
    int tap = ks >> 2, q = ks & 3;
    int ky = tap / 3, kx = tap % 3;
    int cin  = q * 16 + ((l >> 5) << 3) + j;
    int cout = ch * 32 + (l & 31);
    wt[t] = (f16)w[((ky * 3 + kx) * CIN + cin) * COUT_ + cout];
}

__launch_bounds__(256, 2)
__global__ void fused_k(const float* __restrict__ inp,
                        const f16*  __restrict__ wt,
                        const float* __restrict__ cb,
                        const float* __restrict__ gamma,
                        const float* __restrict__ beta,
                        const float* __restrict__ rmean,
                        const float* __restrict__ rvar,
                        const int*  __restrict__ abi,
                        float* __restrict__ out) {
    // patch: 18 rows x 34 cols x 8 channel-groups of 16B (f16x8), XOR-swizzled
    __shared__ uint4 lds[18 * 34 * 8];   // 78336 B -> 2 wg/CU
    __shared__ int act;

    const int wg = blockIdx.x;
    const int tid = threadIdx.x;

    if (wg >= 2 * NACT) {
        // ---- zero-duty: one wg per (bi,bj); zero if block inactive ----
        int b  = wg - 2 * NACT;
        int bi = b >> 5, bj = b & 31;
        if (tid == 0) act = 0;
        __syncthreads();
        int e0 = 2 * tid, e1 = 2 * tid + 1;
        if (abi[3 * e0 + 1] == bi && abi[3 * e0 + 2] == bj) act = 1;
        if (abi[3 * e1 + 1] == bi && abi[3 * e1 + 2] == bj) act = 1;
        __syncthreads();
        if (act) return;
        float4 z = make_float4(0.f, 0.f, 0.f, 0.f);
        float4* base = (float4*)(out + ((size_t)(bi * 32) * IMG_W + bj * 32) * COUT_);
        for (int it = tid; it < 32 * 512; it += 256) {
            int r  = it >> 9;
            int c4 = it & 511;
            base[(size_t)r * (IMG_W * COUT_ / 4) + c4] = z;
        }
        return;
    }

    // ---- conv duty: one wg per half-block (16 rows x 32 cols) ----
    const int ab = wg >> 1, yh = wg & 1;
    const int bi = abi[3 * ab + 1];
    const int bj = abi[3 * ab + 2];
    const int lane = tid & 63;
    const int wv   = tid >> 6;

    // stage 18x34x64 patch (fp32 -> f16, swizzled channel groups)
    const int r0 = bi * 32 + yh * 16 - 1;
    const int c0 = bj * 32 - 1;
    for (int task = tid; task < 18 * 34 * 8; task += 256) {
        int g  = task & 7;
        int p  = task >> 3;
        int dr = p / 34;
        int dc = p - dr * 34;
        int row = r0 + dr, col = c0 + dc;
        float4 a = make_float4(0.f, 0.f, 0.f, 0.f), b = a;
        if ((unsigned)row < IMG_H && (unsigned)col < IMG_W) {
            const float4* src = (const float4*)(inp + (((size_t)row * IMG_W + col) * CIN + g * 8));
            a = src[0]; b = src[1];
        }
        f16x8 v;
        v[0] = (f16)a.x; v[1] = (f16)a.y; v[2] = (f16)a.z; v[3] = (f16)a.w;
        v[4] = (f16)b.x; v[5] = (f16)b.y; v[6] = (f16)b.z; v[7] = (f16)b.w;
        lds[(p << 3) + (g ^ (dc & 7))] = __builtin_bit_cast(uint4, v);
    }

    // per-wave B-fragments: wave = (row-group rg, cout-half chh)
    const int rg  = wv & 1;
    const int chh = wv >> 1;
    f16x8 wf[36];
    const uint4* wt4 = (const uint4*)wt;
    #pragma unroll
    for (int ks = 0; ks < 36; ++ks)
        wf[ks] = __builtin_bit_cast(f16x8, wt4[(ks * 2 + chh) * 64 + lane]);

    const int co = chh * 32 + (lane & 31);
    const float sc = gamma[co] * rsqrtf(rvar[co] + EPS_);
    const float sh = cb[co] * sc + beta[co] - rmean[co] * sc;

    __syncthreads();

    const int px = lane & 31;      // A row = output pixel column
    const int hi = lane >> 5;      // k sub-group
    float* outb = out + (((size_t)(bi * 32 + yh * 16) * IMG_W) + bj * 32) * COUT_;

    for (int yr = 0; yr < 8; ++yr) {
        const int R = rg * 8 + yr;
        f32x16 accA = {0.f,0.f,0.f,0.f,0.f,0.f,0.f,0.f,0.f,0.f,0.f,0.f,0.f,0.f,0.f,0.f};
        f32x16 accB = {0.f,0.f,0.f,0.f,0.f,0.f,0.f,0.f,0.f,0.f,0.f,0.f,0.f,0.f,0.f,0.f};
        #pragma unroll
        for (int ks = 0; ks < 36; ++ks) {
            const int tap = ks >> 2, q = ks & 3;
            const int ky = tap / 3, kx = tap % 3;
            const int dr = R + ky;
            const int dc = px + kx;
            const int slot = (q * 2 + hi) ^ (dc & 7);
            uint4 a = lds[((dr * 34 + dc) << 3) + slot];
            if (ks & 1)
                accB = __builtin_amdgcn_mfma_f32_32x32x16_f16(__builtin_bit_cast(f16x8, a), wf[ks], accB, 0, 0, 0);
            else
                accA = __builtin_amdgcn_mfma_f32_32x32x16_f16(__builtin_bit_cast(f16x8, a), wf[ks], accA, 0, 0, 0);
        }
        #pragma unroll
        for (int r = 0; r < 16; ++r) {
            const int pxo = (r & 3) + 8 * (r >> 2) + 4 * hi;
            float v = fmaxf((accA[r] + accB[r]) * sc + sh, 0.f);
            outb[((size_t)R * IMG_W + pxo) * COUT_ + co] = v;
        }
    }
}

extern "C" void kernel_launch(void* const* d_in, const int* in_sizes, int n_in,
                              void* d_out, int out_size, void* d_ws, size_t ws_size,
                              hipStream_t stream) {
    const float* inp   = (const float*)d_in[0];
    const float* convw = (const float*)d_in[1];
    const float* convb = (const float*)d_in[2];
    const float* gamma = (const float*)d_in[3];
    const float* beta  = (const float*)d_in[4];
    const float* rmean = (const float*)d_in[5];
    const float* rvar  = (const float*)d_in[6];
    const int*   abi   = (const int*)d_in[7];
    float* out = (float*)d_out;

    f16* wt = (f16*)d_ws;

    hipLaunchKernelGGL(prep_weights_k, dim3((WT_ELEMS + 255) / 256), dim3(256), 0, stream, convw, wt);
    hipLaunchKernelGGL(fused_k, dim3(2 * NACT + NBLK * NBLK), dim3(256), 0, stream,
                       inp, wt, convb, gamma, beta, rmean, rvar, abi, out);
}